// Round 6
// baseline (613.823 us; speedup 1.0000x reference)
//
#include <hip/hip_runtime.h>

// GeneralConv_30820685316781 — round 15: gemmt2 full-W-resident. Whole W tile staged to
// dynamic LDS once (32KB hi, +32KB lo when wmode=1), single barrier, then the entire
// kc x n MFMA loop runs barrier-free (A per-lane direct from global, r14 pattern).
#define N_ 40000
#define E_ 320000
#define D_ 128
#define H_ 4
#define T_ 3
#define R_ 5

typedef unsigned short u16;
typedef float f32x4 __attribute__((ext_vector_type(4)));
typedef short s16x8 __attribute__((ext_vector_type(8)));

__device__ __forceinline__ float bf2f(u16 h){ return __uint_as_float(((unsigned)h)<<16); }
__device__ __forceinline__ u16 f2bf(float f){
  unsigned u = __float_as_uint(f);
  u += 0x7fffu + ((u>>16)&1u);     // RNE
  return (u16)(u>>16);
}
__device__ __forceinline__ unsigned fmono(float f){
  unsigned u = __float_as_uint(f);
  return (u>>31) ? ~u : (u | 0x80000000u);
}
__device__ __forceinline__ float monof(unsigned u){
  return (u>>31) ? __uint_as_float(u & 0x7fffffffu) : __uint_as_float(~u);
}
__device__ __forceinline__ float ldx(const void* p, long i, int f32){
  return f32 ? ((const float*)p)[i] : bf2f(((const u16*)p)[i]);
}
__device__ __forceinline__ float wredsum(float v){
  #pragma unroll
  for (int m=32;m;m>>=1) v += __shfl_xor(v, m, 64);
  return v;
}
// split v into bf16 hi (truncated) + bf16 lo (truncated residual); packs 2 elems per u32.
__device__ __forceinline__ void split2(float v0, float v1, unsigned& hp, unsigned& lp){
  unsigned b0 = __float_as_uint(v0), b1 = __float_as_uint(v1);
  unsigned h0 = b0 & 0xFFFF0000u,    h1 = b1 & 0xFFFF0000u;
  float r0 = v0 - __uint_as_float(h0);
  float r1 = v1 - __uint_as_float(h1);
  hp = (h0>>16) | h1;
  lp = (__float_as_uint(r0)>>16) | (__float_as_uint(r1) & 0xFFFF0000u);
}

// wcf element offsets (f32 canonical weight buffer)
#define W_QW 0
#define W_KW 49152
#define W_VW 98304
#define W_AW 147456
#define W_QB 196608
#define W_KB 196992
#define W_VB 197376
#define W_AB 197760
#define W_PRI 198144
#define W_RATT 198164
#define W_RMSG 218644
#define W_WMK 239124
#define W_WAK 288276
#define W_WQ 337428
#define W_BQ 353812
#define W_WKL 353940
#define W_BKL 370324
#define W_SKIP 370452
#define W_LNG 370455
#define W_LNB 370839
#define W_TOT 371223

// Transposed+split weight table offsets, in u16 units relative to (u16*)(w+OFF_WCF).
// Each matrix slot = 32768 u16 (16384 hi then 16384 lo), layout [col][k].
#define WT_Q   0
#define WT_K   98304
#define WT_V   196608
#define WT_A   294912
#define WT_WQ  396328
#define WT_WMK 478248

// ---- workspace layout (bytes). Peak 115,248,896 < proven 115,365,376. ----
#define OFF_FLAGS 0ul
#define OFF_WCF   512ul
#define OFF_NT32  1485824ul
#define OFF_EI32  1646080ul
#define OFF_ET32  4206592ul
#define OFF_PERM  5486592ul    // node perm: 40448 ints, 128-aligned type groups, -1 pad
#define OFF_PCNT  5648384ul    // pcnt[12] | pc2[16] at +128
#define OFF_TVAL  5648896ul    // raT 80KB (s1-s6) | satt/tval 640KB (s7.75+)
#define OFF_NPERM 5730816ul    // 40320 ints, edge-type-sorted first-N edges (s0.8-s7.5)
#define OFF_LOG   6288896ul    // logits 5.12M | mxkey .64M | sumex .64M | deg .16M ; MT+ck+MTt overlay after satt
#define OFF_QN    12848896ul   // qn -> ag0 -> trans
#define OFF_KN    33328896ul   // kn -> ag1
#define OFF_VN    53808896ul   // vn -> ag2
#define OFF_QLIN  74288896ul   // qlin -> hbuf
#define OFF_QTR   94768896ul   // qtrb (s6) -> vp (s7.5-s8)

// ---------------------------------------------------------------------------
__global__ __launch_bounds__(256) void detect_kernel(
    const u16* __restrict__ xs, const int* __restrict__ nt, int* __restrict__ flags)
{
  __shared__ int sBig, sZero, sNz;
  int tid = threadIdx.x;
  if (tid==0){ sBig=0; sZero=0; sNz=0; }
  __syncthreads();
  int big=0, zc=0;
  for (int i=tid; i<1024; i+=256) {
    u16 v = xs[2*i];
    int e = (v>>7)&0xFF;
    big += (e >= 200);
    zc  += (v == 0);
  }
  int nz=0;
  for (int i=tid; i<1024; i+=256) nz += (nt[2*i+1] != 0);
  atomicAdd(&sBig, big); atomicAdd(&sZero, zc); atomicAdd(&sNz, nz);
  __syncthreads();
  if (tid==0) {
    flags[0] = (sBig > 64) || (sZero > 900);
    flags[1] = (sNz == 0);
  }
}

struct FPtrs { const void* p[20]; };
__global__ __launch_bounds__(256) void convf_kernel(
    const int* __restrict__ flags, FPtrs ptrs, float* __restrict__ wcf)
{
  const int start[21] = {0,49152,98304,147456,196608,196992,197376,197760,198144,
    198164,218644,239124,288276,337428,353812,353940,370324,370452,370455,370839,371223};
  int i = blockIdx.x*256 + threadIdx.x;
  if (i >= W_TOT) return;
  int arr = 0;
  #pragma unroll
  for (int a=1; a<20; ++a) arr += (i >= start[a]);
  int local = i - start[arr];
  wcf[i] = ldx(ptrs.p[arr], local, flags[0]);
}

__global__ __launch_bounds__(256) void idxconv_kernel(
    const int* __restrict__ flags,
    const int* __restrict__ nt, const int* __restrict__ ei, const int* __restrict__ et,
    int* __restrict__ nt32, int* __restrict__ ei32, int* __restrict__ et32)
{
  int i = blockIdx.x*256 + threadIdx.x;
  if (i >= 1000000) return;
  int w = flags[1] ? 2 : 1;
  if (i < 40000)        nt32[i] = nt[(long)i*w];
  else if (i < 680000)  { int j=i-40000;  ei32[j] = ei[(long)j*w]; }
  else                  { int j=i-680000; et32[j] = et[(long)j*w]; }
}

// ---- low-contention counting sort (generic, ntypes<=8) ----
__global__ __launch_bounds__(256) void pinit_kernel(int* __restrict__ perm, int* __restrict__ pc){
  int i = blockIdx.x*256 + threadIdx.x;
  if (i < 40448) perm[i] = -1;
  if (i < 12) pc[i] = 0;
}
__global__ __launch_bounds__(256) void einit_kernel(int* __restrict__ nperm, int* __restrict__ pc2){
  int i = blockIdx.x*256 + threadIdx.x;
  if (i < 40320) nperm[i] = -1;
  if (i < 16) pc2[i] = 0;
}
__global__ __launch_bounds__(256) void cnt_kernel(
    const int* __restrict__ keys, int n, int ntypes, int* __restrict__ gcnt)
{
  __shared__ int lh[8];
  if (threadIdx.x < ntypes) lh[threadIdx.x] = 0;
  __syncthreads();
  int i = blockIdx.x*256 + threadIdx.x;
  if (i < n) atomicAdd(&lh[keys[i]], 1);
  __syncthreads();
  if (threadIdx.x < ntypes && lh[threadIdx.x])
    atomicAdd(&gcnt[threadIdx.x], lh[threadIdx.x]);
}
// node groups 128-aligned (gemmt2 has 128-row blocks -> must be type-uniform)
__global__ void pofs_kernel(int* __restrict__ pc){
  if (threadIdx.x==0 && blockIdx.x==0) {
    pc[8] = 0;
    pc[9] = (pc[0]+127)&~127;
    pc[10] = pc[9] + ((pc[1]+127)&~127);
  }
}
// edge groups 64-aligned (gemmbd has 64-row blocks)
__global__ void eofs_kernel(int* __restrict__ pc2){
  if (threadIdx.x==0 && blockIdx.x==0) {
    pc2[10] = 0;
    #pragma unroll
    for (int r=1;r<R_;++r) pc2[10+r] = pc2[10+r-1] + ((pc2[r-1]+63)&~63);
  }
}
__global__ __launch_bounds__(256) void scat_kernel(
    const int* __restrict__ keys, int n, int ntypes,
    const int* __restrict__ ofs, int* __restrict__ fill, int* __restrict__ perm)
{
  __shared__ int lh[8];
  __shared__ int lbase[8];
  if (threadIdx.x < ntypes) lh[threadIdx.x] = 0;
  __syncthreads();
  int i = blockIdx.x*256 + threadIdx.x;
  int t = 0, rank = 0;
  bool ok = (i < n);
  if (ok) { t = keys[i]; rank = atomicAdd(&lh[t], 1); }
  __syncthreads();
  if (threadIdx.x < ntypes)
    lbase[threadIdx.x] = lh[threadIdx.x] ? atomicAdd(&fill[threadIdx.x], lh[threadIdx.x]) : 0;
  __syncthreads();
  if (ok) perm[ofs[t] + lbase[t] + rank] = i;
}

__global__ __launch_bounds__(256) void init_kernel(
    unsigned* __restrict__ mxkey, float* __restrict__ sumex, int* __restrict__ deg)
{
  int i = blockIdx.x*256 + threadIdx.x;   // 625*256 = N*H
  mxkey[i] = fmono(-1e30f);
  sumex[i] = 0.f;
  if (i < N_) deg[i] = 0;
}

// prepA: raT[r][h][m][d] = rel_att[r][h][d][m]
__global__ __launch_bounds__(256) void prepA_kernel(
    const float* __restrict__ wcf, float* __restrict__ raT)
{
  int i = blockIdx.x*256 + threadIdx.x;
  if (i >= 20480) return;
  int d = i & 31, m = (i>>5) & 31, rh = i >> 10;
  raT[i] = wcf[W_RATT + (rh*32 + d)*32 + m];
}

// prepB: MT[k][i*128+col] = sum_j Wak_k[col,j]*Wkl[i,j];  ck[k][col] = sum_j Wak_k[col,j]*bkl[j]
__global__ __launch_bounds__(128) void prepB_kernel(
    const float* __restrict__ wcf, float* __restrict__ MT, float* __restrict__ ck)
{
  int col = threadIdx.x, i = blockIdx.x, k = blockIdx.y;
  const float* wak = wcf + W_WAK + k*16384 + col*128;
  const float* wkl = wcf + W_WKL + i*128;
  float acc = 0.f, accC = 0.f;
  #pragma unroll 8
  for (int j=0;j<128;++j) {
    float a = wak[j];
    acc  += a * wkl[j];
    if (i==0) accC += a * wcf[W_BKL + j];
  }
  MT[k*16384 + i*128 + col] = acc;
  if (i==0) ck[k*128 + col] = accC;
}

// prepT: transpose a [128k][128col] f32/bf16 matrix into split bf16 [col][k] hi|lo slots.
struct TPtrs { const void* p[16]; int soff[16]; int doff[16]; };
__global__ __launch_bounds__(256) void prepT_kernel(
    TPtrs tp, const int* __restrict__ flags, int xmode, u16* __restrict__ dst)
{
  __shared__ float T[128][33];
  int m = blockIdx.y;
  int c0 = blockIdx.x * 32;
  int tid = threadIdx.x;
  int xf = xmode ? 1 : flags[0];
  const void* src = tp.p[m];
  long sb = tp.soff[m];
  {
    int k = tid >> 1, ch = (tid & 1) * 16;
    #pragma unroll
    for (int j=0;j<16;++j)
      T[k][ch+j] = ldx(src, sb + (long)k*128 + c0 + ch + j, xf);
  }
  __syncthreads();
  int col = tid >> 3, k0 = (tid & 7) * 16;
  unsigned hp[8], lp[8];
  #pragma unroll
  for (int j=0;j<8;++j)
    split2(T[k0+2*j][col], T[k0+2*j+1][col], hp[j], lp[j]);
  u16* dh = dst + tp.doff[m] + (long)(c0+col)*128 + k0;
  ((uint4*)dh)[0] = uint4{hp[0],hp[1],hp[2],hp[3]};
  ((uint4*)dh)[1] = uint4{hp[4],hp[5],hp[6],hp[7]};
  u16* dl = dh + 16384;
  ((uint4*)dl)[0] = uint4{lp[0],lp[1],lp[2],lp[3]};
  ((uint4*)dl)[1] = uint4{lp[4],lp[5],lp[6],lp[7]};
}

// ---------------------------------------------------------------------------
// gemmt2 (MFMA, full-W-resident): block = 128 rows x 128 cols, 4 waves.
// W tile (hi, + lo when wlds) staged to dynamic LDS ONCE with chunk-XOR swizzle
// (pos = (kc*4+chunk) ^ (col&15) -> uniform 8 slots/bank for ds_read_b128), then the
// whole kc x n loop runs with no barriers: per-lane A global loads + LDS reads + MFMA.
// A transform (pow / hi-lo split) in registers. Padded rows clamp to 0, guard-skipped.
// Fallback: wlo needed but not staged (f32 harness, wmode=0) -> Wl read from global.
struct GC4 { const float* x[4]; int woff[4]; int boff[4]; int typed[4]; };
__global__ __launch_bounds__(256) void gemmt2_kernel(
    GC4 cfg, const int* __restrict__ flags, int xmode,
    const u16* __restrict__ Wt, const float* __restrict__ wcf,
    const int* __restrict__ perm, const int* __restrict__ nt,
    int dotmode, const float* __restrict__ qlin, const float* __restrict__ ck,
    int powmode, const float* __restrict__ sattp, int wmode, int wlds,
    float* __restrict__ out, long yostride)
{
  extern __shared__ u16 smem[];    // Wh[16384] (+ Wl[16384] when wlds)
  __shared__ int ridx[128];
  __shared__ int tblk_s;
  int tid = threadIdx.x;
  int y = blockIdx.y;
  int row0 = blockIdx.x*128;
  if (tid < 128) {
    int rr = row0 + tid;
    int rg = perm ? perm[rr] : (rr < N_ ? rr : -1);
    ridx[tid] = rg;
    if (tid==0) tblk_s = (perm && nt && rg>=0) ? nt[rg] : 0;
  }
  __syncthreads();
  if (ridx[0] < 0) return;        // fully padded block (128-aligned groups -> uniform)
  int tblk = cfg.typed[y] ? tblk_s : 0;
  const u16* Wg = Wt + cfg.woff[y] + tblk*32768;
  const void* X = (const void*)cfg.x[y];
  int xf = xmode ? 1 : flags[0];
  int wlo_on = wmode ? 1 : flags[0];

  // ---- stage full W tile (hi, + lo when wlds): 8 (16) uint4 per thread ----
  {
    int col = tid >> 1, half = tid & 1;
    int key = col & 15;
    #pragma unroll
    for (int kc=0;kc<4;++kc) {
      const uint4* gh = reinterpret_cast<const uint4*>(Wg + col*128 + kc*32 + half*16);
      uint4 v0 = gh[0], v1 = gh[1];
      int c0 = kc*4 + half*2;
      ((uint4*)smem)[col*16 + (c0 ^ key)]       = v0;
      ((uint4*)smem)[col*16 + ((c0+1) ^ key)]   = v1;
      if (wlds && wlo_on) {
        const uint4* gl = reinterpret_cast<const uint4*>(Wg + 16384 + col*128 + kc*32 + half*16);
        uint4 w0 = gl[0], w1 = gl[1];
        ((uint4*)(smem+16384))[col*16 + (c0 ^ key)]     = w0;
        ((uint4*)(smem+16384))[col*16 + ((c0+1) ^ key)] = w1;
      }
    }
  }
  __syncthreads();                 // only barrier; loop below is sync-free

  int lane = tid & 63;
  int wv   = tid >> 6;
  int lrow = lane & 15;
  int lkq  = lane >> 4;            // 0..3
  int lk   = lkq << 3;
  int rbase = wv*32;

  // this lane's two A rows (m=0,1); padded rows clamp to 0 (outputs guard-skipped)
  int sr0i = ridx[rbase + lrow];
  int sr1i = ridx[rbase + lrow + 16];
  long s0 = (sr0i < 0) ? 0 : (long)sr0i;
  long s1 = (sr1i < 0) ? 0 : (long)sr1i;

  f32x4 acc[2][8];
  #pragma unroll
  for (int m=0;m<2;++m)
    #pragma unroll
    for (int n=0;n<8;++n) acc[m][n] = f32x4{0.f,0.f,0.f,0.f};

  // ---- A prefetch registers ----
  float4 fa0, fa1, fb0, fb1;                 // f32 A rows (r0: fa*, r1: fb*)
  uint4  ua = {0,0,0,0}, ub = {0,0,0,0};     // bf16 A raw
  float  scp0 = 0.f, scp1 = 0.f;             // powmode per-row scales

  if (xf) {
    const float4* x0 = reinterpret_cast<const float4*>((const float*)X + s0*128 + lk);
    const float4* x1 = reinterpret_cast<const float4*>((const float*)X + s1*128 + lk);
    fa0=x0[0]; fa1=x0[1]; fb0=x1[0]; fb1=x1[1];
    if (powmode) { scp0 = sattp[s0*4]; scp1 = sattp[s1*4]; }
  } else {
    ua = *reinterpret_cast<const uint4*>((const u16*)X + s0*128 + lk);
    ub = *reinterpret_cast<const uint4*>((const u16*)X + s1*128 + lk);
  }

  #pragma unroll
  for (int kc=0;kc<4;++kc) {
    // ---- transform current prefetched A into fragments (register-only) ----
    s16x8 ah0, ah1, al0, al1;
    if (xf) {
      float t0[8] = {fa0.x,fa0.y,fa0.z,fa0.w, fa1.x,fa1.y,fa1.z,fa1.w};
      float t1[8] = {fb0.x,fb0.y,fb0.z,fb0.w, fb1.x,fb1.y,fb1.z,fb1.w};
      if (powmode) {
        #pragma unroll
        for (int j=0;j<8;++j) {
          float v0 = t0[j], v1 = t1[j];
          if (y==0)      { t0[j] = v0*scp0;    t1[j] = v1*scp1; }
          else if (y==1) { t0[j] = v0*v0*scp0; t1[j] = v1*v1*scp1; }
          else {
            float a3 = v0*v0*v0*scp0, b3 = v1*v1*v1*scp1;
            t0[j] = (a3==0.f) ? 0.f : copysignf(cbrtf(fabsf(a3)+1e-18f), a3);
            t1[j] = (b3==0.f) ? 0.f : copysignf(cbrtf(fabsf(b3)+1e-18f), b3);
          }
        }
      }
      unsigned h0[4], l0[4], h1[4], l1[4];
      #pragma unroll
      for (int j=0;j<4;++j) {
        split2(t0[2*j], t0[2*j+1], h0[j], l0[j]);
        split2(t1[2*j], t1[2*j+1], h1[j], l1[j]);
      }
      uint4 H0{h0[0],h0[1],h0[2],h0[3]}, L0{l0[0],l0[1],l0[2],l0[3]};
      uint4 H1{h1[0],h1[1],h1[2],h1[3]}, L1{l1[0],l1[1],l1[2],l1[3]};
      ah0 = *reinterpret_cast<s16x8*>(&H0); al0 = *reinterpret_cast<s16x8*>(&L0);
      ah1 = *reinterpret_cast<s16x8*>(&H1); al1 = *reinterpret_cast<s16x8*>(&L1);
    } else {
      ah0 = *reinterpret_cast<s16x8*>(&ua);   // bf16 input: hi == raw bits, lo == 0
      ah1 = *reinterpret_cast<s16x8*>(&ub);
    }
    // ---- issue next-kc A loads (latency hides under MFMA, no barrier in the way) ----
    if (kc < 3) {
      int kn_ = kc + 1;
      if (xf) {
        const float4* x0 = reinterpret_cast<const float4*>((const float*)X + s0*128 + kn_*32 + lk);
        const float4* x1 = reinterpret_cast<const float4*>((const float*)X + s1*128 + kn_*32 + lk);
        fa0=x0[0]; fa1=x0[1]; fb0=x1[0]; fb1=x1[1];
        if (powmode) { scp0 = sattp[s0*4 + kn_]; scp1 = sattp[s1*4 + kn_]; }
      } else {
        ua = *reinterpret_cast<const uint4*>((const u16*)X + s0*128 + kn_*32 + lk);
        ub = *reinterpret_cast<const uint4*>((const u16*)X + s1*128 + kn_*32 + lk);
      }
    }
    // ---- LDS fragment reads + MFMA (sync-free) ----
    #pragma unroll
    for (int n=0;n<8;++n) {
      int col = n*16 + lrow;
      int ibh = col*128 + (((kc*4 + lkq) ^ lrow) << 3);   // col&15 == lrow
      s16x8 bh = *(const s16x8*)(smem + ibh);
      acc[0][n] = __builtin_amdgcn_mfma_f32_16x16x32_bf16(ah0, bh, acc[0][n], 0,0,0);
      acc[1][n] = __builtin_amdgcn_mfma_f32_16x16x32_bf16(ah1, bh, acc[1][n], 0,0,0);
      if (xf) {
        acc[0][n] = __builtin_amdgcn_mfma_f32_16x16x32_bf16(al0, bh, acc[0][n], 0,0,0);
        acc[1][n] = __builtin_amdgcn_mfma_f32_16x16x32_bf16(al1, bh, acc[1][n], 0,0,0);
      }
      if (wlo_on) {
        s16x8 bl = wlds ? *(const s16x8*)(smem + 16384 + ibh)
                        : *(const s16x8*)(Wg + 16384 + col*128 + kc*32 + lk);
        acc[0][n] = __builtin_amdgcn_mfma_f32_16x16x32_bf16(ah0, bl, acc[0][n], 0,0,0);
        acc[1][n] = __builtin_amdgcn_mfma_f32_16x16x32_bf16(ah1, bl, acc[1][n], 0,0,0);
      }
    }
  }

  // D layout per 16x16 frag: row = (lane>>4)*4 + r, col = lane&15.
  int rq = lkq << 2;
  if (!dotmode) {
    float b[8];
    if (cfg.boff[y] >= 0) {
      const float* bp = wcf + cfg.boff[y] + tblk*128;
      #pragma unroll
      for (int n=0;n<8;++n) b[n] = bp[n*16 + lrow];
    } else {
      #pragma unroll
      for (int n=0;n<8;++n) b[n] = 0.f;
    }
    #pragma unroll
    for (int m=0;m<2;++m) {
      #pragma unroll
      for (int r=0;r<4;++r) {
        int rowl = rbase + m*16 + rq + r;
        int rowg = ridx[rowl];
        if (rowg < 0) continue;
        float* op = out + (long)y*yostride + (long)rowg*128 + lrow;
        #pragma unroll
        for (int n=0;n<8;++n) op[n*16] = acc[m][n][r] + b[n];
      }
    }
  } else {
    float ckv[8];
    #pragma unroll
    for (int n=0;n<8;++n) ckv[n] = ck[y*128 + n*16 + lrow];
    #pragma unroll
    for (int m=0;m<2;++m) {
      #pragma unroll
      for (int r=0;r<4;++r) {
        int rowl = rbase + m*16 + rq + r;
        int rowg = ridx[rowl];
        float d = 0.f;
        if (rowg >= 0) {
          const float* qp = qlin + (long)rowg*128 + lrow;
          #pragma unroll
          for (int n=0;n<8;++n) d += (acc[m][n][r] + ckv[n]) * qp[n*16];
        }
        #pragma unroll
        for (int msk=1; msk<16; msk<<=1) d += __shfl_xor(d, msk, 64);
        if (lrow==0 && rowg>=0) out[(long)rowg*4 + y] = 1.f/(1.f+expf(-d));
      }
    }
  }
}

// ---------------------------------------------------------------------------
// gemmbd: block-diagonal (4 heads x 32x32) GEMM, 64 rows x 128 cols per block.
__global__ __launch_bounds__(256) void gemmbd_kernel(
    const float* __restrict__ X,
    const float* __restrict__ Wtab, int wsel,
    const int* __restrict__ perm, const int* __restrict__ gsrc, const int* __restrict__ et,
    float* __restrict__ out)
{
  __shared__ float As[64*152];    // [row][h*36 + m], bank-staggered
  __shared__ float Ws[4096];
  __shared__ int ridx[64];
  __shared__ int rsel_s;
  int tid = threadIdx.x;
  int row0 = blockIdx.x*64;
  if (tid < 64) {
    int rr = row0 + tid;
    int pe = perm ? perm[rr] : (rr < N_ ? rr : -1);
    ridx[tid] = pe;
    if (tid == 0) rsel_s = (wsel && pe >= 0) ? et[pe] : 0;
  }
  __syncthreads();
  if (ridx[0] < 0) return;
  const float* Wg = Wtab + (long)(wsel ? rsel_s : 0)*4096;
  #pragma unroll
  for (int j=0;j<4;++j)
    *reinterpret_cast<float4*>(&Ws[j*1024 + tid*4]) =
      *reinterpret_cast<const float4*>(Wg + j*1024 + tid*4);
  {
    int sar = tid >> 2, sh = tid & 3;
    int pe_s = ridx[sar];
    int arow = (pe_s < 0) ? -1 : (gsrc ? gsrc[pe_s] : pe_s);
    float* dst = &As[sar*152 + sh*36];
    if (arow < 0) {
      #pragma unroll
      for (int j=0;j<8;++j) *reinterpret_cast<float4*>(dst + j*4) = float4{0.f,0.f,0.f,0.f};
    } else {
      const float4* s4 = reinterpret_cast<const float4*>(X + (long)arow*128 + sh*32);
      #pragma unroll
      for (int j=0;j<8;++j) *reinterpret_cast<float4*>(dst + j*4) = s4[j];
    }
  }
  __syncthreads();
  int rg_ = tid >> 5, cg = tid & 31;
  int h = cg >> 3, c4 = (cg & 7)*4;
  float acc[8][4];
  #pragma unroll
  for (int r=0;r<8;++r){ acc[r][0]=0.f; acc[r][1]=0.f; acc[r][2]=0.f; acc[r][3]=0.f; }
  #pragma unroll
  for (int mq=0;mq<8;++mq) {
    float wv[4][4];
    #pragma unroll
    for (int i=0;i<4;++i) {
      float4 wt = *reinterpret_cast<const float4*>(&Ws[h*1024 + (mq*4+i)*32 + c4]);
      wv[i][0]=wt.x; wv[i][1]=wt.y; wv[i][2]=wt.z; wv[i][3]=wt.w;
    }
    #pragma unroll
    for (int r=0;r<8;++r) {
      float4 a4 = *reinterpret_cast<const float4*>(&As[(rg_*8+r)*152 + h*36 + mq*4]);
      float av[4] = {a4.x,a4.y,a4.z,a4.w};
      #pragma unroll
      for (int i=0;i<4;++i) {
        acc[r][0]+=av[i]*wv[i][0]; acc[r][1]+=av[i]*wv[i][1];
        acc[r][2]+=av[i]*wv[i][2]; acc[r][3]+=av[i]*wv[i][3];
      }
    }
  }
  #pragma unroll
  for (int r=0;r<8;++r) {
    int pe = ridx[rg_*8+r];
    if (pe < 0) continue;
    float4 o = {acc[r][0],acc[r][1],acc[r][2],acc[r][3]};
    *reinterpret_cast<float4*>(out + (long)pe*128 + h*32 + c4) = o;
  }
}

// ---------------------------------------------------------------------------
__global__ __launch_bounds__(256) void epass_kernel(
    const float* __restrict__ kn, const float* __restrict__ qtr, const float* __restrict__ wcf,
    const int* __restrict__ ei, const int* __restrict__ et, int rsel,
    float* __restrict__ logits, unsigned* __restrict__ mxkey, int* __restrict__ deg)
{
  int gid = blockIdx.x*256 + threadIdx.x;   // E*H
  int e = gid >> 2, h = gid & 3;
  if (et[e] != rsel) return;
  int s = ei[e], t = ei[E_+e];
  const float4* ka = reinterpret_cast<const float4*>(kn + (long)s*128 + h*32);
  const float4* qa = reinterpret_cast<const float4*>(qtr + (long)t*128 + h*32);
  float acc = 0.f;
  #pragma unroll
  for (int i=0;i<8;++i) {
    float4 a = ka[i], b = qa[i];
    acc += a.x*b.x + a.y*b.y + a.z*b.z + a.w*b.w;
  }
  float lg = acc * wcf[W_PRI + rsel*H_+h] * 0.17677669529663687f;
  logits[gid] = lg;
  atomicMax(mxkey + t*H_+h, fmono(lg));
  if (h==0) atomicAdd(deg + t, 1);
}

__global__ __launch_bounds__(256) void eexp_kernel(
    const int* __restrict__ ei, float* __restrict__ logits,
    const unsigned* __restrict__ mxkey, float* __restrict__ sumex)
{
  int gid = blockIdx.x*256 + threadIdx.x;
  int e = gid >> 2, h = gid & 3;
  int t = ei[E_+e];
  float d = fminf(logits[gid] - monof(mxkey[t*H_+h]), 0.f);
  float ex = expf(d);
  if (e < N_) logits[gid] = ex;    // only first-N edges' ex are ever read (satt)
  atomicAdd(sumex + t*H_+h, ex);
}

// satt[n*4+h] = deg[n] * ex[n*4+h] / (sumex[tgt[n]*4+h] + 1e-16)
__global__ __launch_bounds__(256) void satt_kernel(
    const int* __restrict__ ei, const float* __restrict__ ex, const float* __restrict__ sumex,
    const int* __restrict__ deg, float* __restrict__ satt)
{
  int i = blockIdx.x*256 + threadIdx.x;   // N*H
  int n = i >> 2, h = i & 3;
  int t = ei[E_+n];
  satt[i] = (float)deg[n] * ex[i] / (sumex[t*H_+h] + 1e-16f);
}

// gatemix: res = sum_k t_k·ag_k; h = gelu_exact(res)
__global__ __launch_bounds__(256) void gatemix_kernel(
    const float* __restrict__ tval,
    const float* __restrict__ ag0, const float* __restrict__ ag1, const float* __restrict__ ag2,
    float* __restrict__ hout)
{
  long gid = (long)blockIdx.x*256 + threadIdx.x;   // N*128
  int n = (int)(gid >> 7);
  float res = tval[n*4+0]*ag0[gid] + tval[n*4+1]*ag1[gid] + tval[n*4+2]*ag2[gid];
  hout[gid] = 0.5f*res*(1.f+erff(res*0.70710678118654752f));
}

__global__ __launch_bounds__(256) void lnf_kernel(
    const float* __restrict__ trans, const void* __restrict__ x, const int* __restrict__ flags,
    const int* __restrict__ nt, const float* __restrict__ wcf, void* __restrict__ outv)
{
  int wave = threadIdx.x >> 6, lane = threadIdx.x & 63;
  int n = blockIdx.x*4 + wave;
  int j = lane*2;
  int xf = flags[0];
  int t = nt[n];
  float alpha = 1.f/(1.f+expf(-wcf[W_SKIP+t]));
  long base = (long)n*128 + j;
  float y0 = alpha*trans[base]   + (1.f-alpha)*ldx(x, base,   xf);
  float y1 = alpha*trans[base+1] + (1.f-alpha)*ldx(x, base+1, xf);
  float mu = wredsum(y0+y1) * (1.f/128.f);
  float d0 = y0-mu, d1 = y1-mu;
  float var = wredsum(d0*d0+d1*d1) * (1.f/128.f);
  float inv = rsqrtf(var + 1e-5f);
  float o0 = d0*inv*wcf[W_LNG + t*128+j]   + wcf[W_LNB + t*128+j];
  float o1 = d1*inv*wcf[W_LNG + t*128+j+1] + wcf[W_LNB + t*128+j+1];
  if (xf) {
    ((float*)outv)[base]   = o0;
    ((float*)outv)[base+1] = o1;
  } else {
    unsigned o = (unsigned)f2bf(o0) | ((unsigned)f2bf(o1)<<16);
    *reinterpret_cast<unsigned*>(((u16*)outv)+base) = o;
  }
}

// ---------------------------------------------------------------------------
extern "C" void kernel_launch(void* const* d_in, const int* in_sizes, int n_in,
                              void* d_out, int out_size, void* d_ws, size_t ws_size,
                              hipStream_t stream) {
  char* w = (char*)d_ws;
  int*      flags = (int*)     (w + OFF_FLAGS);
  float*    wcf   = (float*)   (w + OFF_WCF);
  u16*      wtb   = (u16*)     (w + OFF_WCF);   // split-transposed weight tables overlay
  int*      nt32  = (int*)     (w + OFF_NT32);
  int*      ei32  = (int*)     (w + OFF_EI32);
  int*      et32  = (int*)     (w + OFF_ET32);
  int*      perm  = (int*)     (w + OFF_PERM);
  int*      pcnt  = (int*)     (w + OFF_PCNT);
  int*      pc2   = (int*)     (w + OFF_PCNT + 128);
  float*    raT   = (float*)   (w + OFF_TVAL);   // raT -> satt/tval (disjoint lifetimes)
  float*    satt  = (float*)   (w + OFF_TVAL);
  float*    tval  = (float*)   (w + OFF_TVAL);
  int*      nperm = (int*)     (w + OFF_NPERM);
  float*    logits= (float*)   (w + OFF_LOG);
  unsigned* mxkey = (unsigned*)(w + OFF_LOG + 5120000);
  float*    sumex = (float*)   (w + OFF_LOG + 5760000);
  int*      deg   = (int*)     (w + OFF_LOG + 6400000);
  float*    MT    = (float*)   (w + OFF_LOG);            // overlays dead softmax scratch
  float*    ckb   = (float*)   (w + OFF_LOG + 786432);
  u16*      mtt   = (u16*)     (w + OFF_LOG + 1048576);  // split-transposed MT (3 slots)
  float*    qn    = (float*)   (w + OFF_QN);
  float*    ag0   = (float*)   (w + OFF_QN);
  float*    trans = (float*)   (w + OFF_QN);
  float*    kn    = (float*)   (w + OFF_KN);
  float*    ag1   = (float*)   (w + OFF_KN);
  float*    vn    = (float*)   (w + OFF_VN);
  float*    ag2   = (float*)   (w + OFF_VN);
  float*    qlin  = (float*)   (w + OFF_QLIN);
  float*    hbuf  = (float*)   (w + OFF_QLIN);
  float*    qtrb  = (float*)   (w + OFF_QTR);
  float*    vp    = (float*)   (w + OFF_QTR);

  // s0: dtype detect + canonicalize
  detect_kernel<<<1,256,0,stream>>>((const u16*)d_in[0], (const int*)d_in[1], flags);
  FPtrs fp;
  fp.p[0]=d_in[5];  fp.p[1]=d_in[7];  fp.p[2]=d_in[9];  fp.p[3]=d_in[11];
  fp.p[4]=d_in[6];  fp.p[5]=d_in[8];  fp.p[6]=d_in[10]; fp.p[7]=d_in[12];
  fp.p[8]=d_in[13]; fp.p[9]=d_in[14]; fp.p[10]=d_in[15];fp.p[11]=d_in[16];
  fp.p[12]=d_in[17];fp.p[13]=d_in[18];fp.p[14]=d_in[19];fp.p[15]=d_in[20];
  fp.p[16]=d_in[21];fp.p[17]=d_in[22];fp.p[18]=d_in[23];fp.p[19]=d_in[24];
  convf_kernel<<<1451,256,0,stream>>>(flags, fp, wcf);
  idxconv_kernel<<<3907,256,0,stream>>>(flags, (const int*)d_in[1],
                                        (const int*)d_in[2], (const int*)d_in[3],
                                        nt32, ei32, et32);
  // s0.7: node-type perm (128-aligned groups)
  pinit_kernel<<<159,256,0,stream>>>(perm, pcnt);
  cnt_kernel  <<<157,256,0,stream>>>(nt32, N_, T_, pcnt);
  pofs_kernel <<<1,64,0,stream>>>(pcnt);
  scat_kernel <<<157,256,0,stream>>>(nt32, N_, T_, pcnt+8, pcnt+4, perm);
  // s0.8: edge-type perm over first N edges (64-aligned groups)
  einit_kernel<<<158,256,0,stream>>>(nperm, pc2);
  cnt_kernel  <<<157,256,0,stream>>>(et32, N_, R_, pc2);
  eofs_kernel <<<1,64,0,stream>>>(pc2);
  scat_kernel <<<157,256,0,stream>>>(et32, N_, R_, pc2+10, pc2+5, nperm);
  // s1: raT (reads W_RATT f32 — must precede prepT which overlays that region)
  prepA_kernel<<<80,256,0,stream>>>(wcf, raT);

  // s1.5: split-transposed bf16 weight tables from original inputs (overlay dead wcf slots)
  TPtrs tps;
  for (int t=0;t<3;++t) {
    tps.p[t]    = d_in[5];  tps.soff[t]    = t*16384; tps.doff[t]    = WT_Q   + t*32768;
    tps.p[3+t]  = d_in[7];  tps.soff[3+t]  = t*16384; tps.doff[3+t]  = WT_K   + t*32768;
    tps.p[6+t]  = d_in[9];  tps.soff[6+t]  = t*16384; tps.doff[6+t]  = WT_V   + t*32768;
    tps.p[9+t]  = d_in[11]; tps.soff[9+t]  = t*16384; tps.doff[9+t]  = WT_A   + t*32768;
    tps.p[13+t] = d_in[16]; tps.soff[13+t] = t*16384; tps.doff[13+t] = WT_WMK + t*32768;
  }
  tps.p[12] = d_in[18]; tps.soff[12] = 0; tps.doff[12] = WT_WQ;
  prepT_kernel<<<dim3(4,16),256,0,stream>>>(tps, flags, 0, wtb);

  // s2: q/k/v/qlin projections in ONE y=4 dispatch (qn,kn,vn,qlin contiguous at stride 5.12M)
  GC4 cq;
  cq.x[0]=(const float*)d_in[0]; cq.x[1]=cq.x[0]; cq.x[2]=cq.x[0]; cq.x[3]=cq.x[0];
  cq.woff[0]=WT_Q; cq.woff[1]=WT_K; cq.woff[2]=WT_V; cq.woff[3]=WT_WQ;
  cq.boff[0]=W_QB; cq.boff[1]=W_KB; cq.boff[2]=W_VB; cq.boff[3]=W_BQ;
  cq.typed[0]=1; cq.typed[1]=1; cq.typed[2]=1; cq.typed[3]=0;
  gemmt2_kernel<<<dim3(316,4),256,32768,stream>>>(cq, flags, 0, wtb, wcf, perm, nt32,
      0, nullptr, nullptr, 0, nullptr, 0, 0, qn, 5120000);

  // s5.5: init softmax accumulators
  init_kernel<<<625,256,0,stream>>>(mxkey, sumex, deg);

  // s6: per-relation qtr (gemmbd) + edge pass
  for (int r=0; r<R_; ++r) {
    gemmbd_kernel<<<625,256,0,stream>>>(qn, raT + r*4096, 0, nullptr, nullptr, nullptr, qtrb);
    epass_kernel<<<5000,256,0,stream>>>(kn, qtrb, wcf, ei32, et32, r, logits, mxkey, deg);
  }
  // s7: exp + segment-sum
  eexp_kernel<<<5000,256,0,stream>>>(ei32, logits, mxkey, sumex);

  // s7.5: vp[n] = vn[src[n]] @ BD(rel_msg[et[n]])  (edge-type-sorted blocks)
  gemmbd_kernel<<<630,256,0,stream>>>(vn, wcf+W_RMSG, 1, nperm, ei32, et32, vp);

  // s7.75: satt = deg·ex/sumex  (softmax scratch dead after this)
  satt_kernel<<<625,256,0,stream>>>(ei32, logits, sumex, deg, satt);

  // s8.25: MT/ck into dead softmax region, then split-transpose MT -> mtt
  prepB_kernel<<<dim3(128,3),128,0,stream>>>(wcf, MT, ckb);
  TPtrs tpm;
  for (int i=0;i<16;++i){ tpm.p[i]=MT; tpm.soff[i]=0; tpm.doff[i]=0; }
  for (int k=0;k<3;++k){ tpm.soff[k]=k*16384; tpm.doff[k]=k*32768; }
  prepT_kernel<<<dim3(4,3),256,0,stream>>>(tpm, flags, 1, mtt);

  // s8.5: ag_k = pow_k(vp)·satt @ WMk[k]  (powmode, batched k)
  GC4 cp;
  cp.x[0]=vp; cp.x[1]=vp; cp.x[2]=vp; cp.x[3]=vp;
  cp.woff[0]=WT_WMK; cp.woff[1]=WT_WMK+32768; cp.woff[2]=WT_WMK+65536; cp.woff[3]=0;
  cp.boff[0]=-1; cp.boff[1]=-1; cp.boff[2]=-1; cp.boff[3]=-1;
  cp.typed[0]=0; cp.typed[1]=0; cp.typed[2]=0; cp.typed[3]=0;
  gemmt2_kernel<<<dim3(313,3),256,32768,stream>>>(cp, flags, 1, wtb, wcf, nullptr, nullptr,
      0, nullptr, nullptr, 1, satt, 0, 0, ag0, 5120000);

  // s9: gate scalars (dot-mode; MT is f32-computed -> wmode=1 keeps lo term, staged in LDS)
  GC4 cd;
  cd.x[0]=ag0; cd.x[1]=ag1; cd.x[2]=ag2; cd.x[3]=ag2;
  cd.woff[0]=0; cd.woff[1]=32768; cd.woff[2]=65536; cd.woff[3]=0;
  cd.boff[0]=-1; cd.boff[1]=-1; cd.boff[2]=-1; cd.boff[3]=-1;
  cd.typed[0]=0; cd.typed[1]=0; cd.typed[2]=0; cd.typed[3]=0;
  gemmt2_kernel<<<dim3(313,3),256,65536,stream>>>(cd, flags, 1, mtt, wcf, nullptr, nullptr,
      1, qlin, ckb, 0, nullptr, 1, 1, tval, 0);

  // s10: mix + gelu -> hbuf (overlays qlin; qlin dead after dot-mode)
  gatemix_kernel<<<20000,256,0,stream>>>(tval, ag0, ag1, ag2, hbuf);

  // s11: trans = typed(h, a_w, a_b)
  GC4 ct;
  ct.x[0]=hbuf; ct.x[1]=hbuf; ct.x[2]=hbuf; ct.x[3]=hbuf;
  ct.woff[0]=WT_A; ct.woff[1]=0; ct.woff[2]=0; ct.woff[3]=0;
  ct.boff[0]=W_AB; ct.boff[1]=-1; ct.boff[2]=-1; ct.boff[3]=-1;
  ct.typed[0]=1; ct.typed[1]=0; ct.typed[2]=0; ct.typed[3]=0;
  gemmt2_kernel<<<dim3(316,1),256,32768,stream>>>(ct, flags, 1, wtb, wcf, perm, nt32,
      0, nullptr, nullptr, 0, nullptr, 0, 0, trans, 0);

  // s12: skip-mix + per-type LayerNorm -> out
  lnf_kernel<<<10000,256,0,stream>>>(trans, d_in[0], flags, nt32, wcf, d_out);

  (void)in_sizes; (void)n_in; (void)out_size; (void)ws_size;
}

// Round 8
// 542.866 us; speedup vs baseline: 1.1307x; 1.1307x over previous
//
#include <hip/hip_runtime.h>

// GeneralConv_30820685316781 — round 17: edge path reverted to f32 (r14). bf16 compression
// moved to the post-softmax linear path, gated on bf16-harness (!flags[0]): ag0/1/2 and
// hbuf stored bf16 -> ~110MB less traffic in s8.5/s9/gatemix/s11. zinit fusion kept.
#define N_ 40000
#define E_ 320000
#define D_ 128
#define H_ 4
#define T_ 3
#define R_ 5

typedef unsigned short u16;
typedef float f32x4 __attribute__((ext_vector_type(4)));
typedef short s16x8 __attribute__((ext_vector_type(8)));

__device__ __forceinline__ float bf2f(u16 h){ return __uint_as_float(((unsigned)h)<<16); }
__device__ __forceinline__ u16 f2bf(float f){
  unsigned u = __float_as_uint(f);
  u += 0x7fffu + ((u>>16)&1u);     // RNE
  return (u16)(u>>16);
}
__device__ __forceinline__ unsigned fmono(float f){
  unsigned u = __float_as_uint(f);
  return (u>>31) ? ~u : (u | 0x80000000u);
}
__device__ __forceinline__ float monof(unsigned u){
  return (u>>31) ? __uint_as_float(u & 0x7fffffffu) : __uint_as_float(~u);
}
__device__ __forceinline__ float ldx(const void* p, long i, int f32){
  return f32 ? ((const float*)p)[i] : bf2f(((const u16*)p)[i]);
}
__device__ __forceinline__ float wredsum(float v){
  #pragma unroll
  for (int m=32;m;m>>=1) v += __shfl_xor(v, m, 64);
  return v;
}
// split v into bf16 hi (truncated) + bf16 lo (truncated residual); packs 2 elems per u32.
__device__ __forceinline__ void split2(float v0, float v1, unsigned& hp, unsigned& lp){
  unsigned b0 = __float_as_uint(v0), b1 = __float_as_uint(v1);
  unsigned h0 = b0 & 0xFFFF0000u,    h1 = b1 & 0xFFFF0000u;
  float r0 = v0 - __uint_as_float(h0);
  float r1 = v1 - __uint_as_float(h1);
  hp = (h0>>16) | h1;
  lp = (__float_as_uint(r0)>>16) | (__float_as_uint(r1) & 0xFFFF0000u);
}

// wcf element offsets (f32 canonical weight buffer)
#define W_QW 0
#define W_KW 49152
#define W_VW 98304
#define W_AW 147456
#define W_QB 196608
#define W_KB 196992
#define W_VB 197376
#define W_AB 197760
#define W_PRI 198144
#define W_RATT 198164
#define W_RMSG 218644
#define W_WMK 239124
#define W_WAK 288276
#define W_WQ 337428
#define W_BQ 353812
#define W_WKL 353940
#define W_BKL 370324
#define W_SKIP 370452
#define W_LNG 370455
#define W_LNB 370839
#define W_TOT 371223

// Transposed+split weight table offsets, in u16 units relative to (u16*)(w+OFF_WCF).
// Each matrix slot = 32768 u16 (16384 hi then 16384 lo), layout [col][k].
#define WT_Q   0
#define WT_K   98304
#define WT_V   196608
#define WT_A   294912
#define WT_WQ  396328
#define WT_WMK 478248

// ---- workspace layout (bytes). Peak 115,248,896 < proven 115,365,376. ----
#define OFF_FLAGS 0ul
#define OFF_WCF   512ul
#define OFF_NT32  1485824ul
#define OFF_EI32  1646080ul
#define OFF_ET32  4206592ul
#define OFF_PERM  5486592ul    // node perm: 40448 ints, 128-aligned type groups, -1 pad
#define OFF_PCNT  5648384ul    // pcnt[12] | pc2[16] at +128
#define OFF_TVAL  5648896ul    // raT 80KB (s1-s6) | satt/tval 640KB (s7.75+)
#define OFF_NPERM 5730816ul    // 40320 ints, edge-type-sorted first-N edges (s0.8-s7.5)
#define OFF_LOG   6288896ul    // logits 5.12M | mxkey .64M | sumex .64M | deg .16M ; MT+ck+MTt overlay after satt
#define OFF_QN    12848896ul   // qn -> ag0 (bf16) -> trans
#define OFF_KN    33328896ul   // kn -> ag1 (bf16)
#define OFF_VN    53808896ul   // vn -> ag2 (bf16)
#define OFF_QLIN  74288896ul   // qlin -> hbuf (bf16)
#define OFF_QTR   94768896ul   // qtrb (s6) -> vp (s7.5-s8)

// ---------------------------------------------------------------------------
__global__ __launch_bounds__(256) void detect_kernel(
    const u16* __restrict__ xs, const int* __restrict__ nt, int* __restrict__ flags)
{
  __shared__ int sBig, sZero, sNz;
  int tid = threadIdx.x;
  if (tid==0){ sBig=0; sZero=0; sNz=0; }
  __syncthreads();
  int big=0, zc=0;
  for (int i=tid; i<1024; i+=256) {
    u16 v = xs[2*i];
    int e = (v>>7)&0xFF;
    big += (e >= 200);
    zc  += (v == 0);
  }
  int nz=0;
  for (int i=tid; i<1024; i+=256) nz += (nt[2*i+1] != 0);
  atomicAdd(&sBig, big); atomicAdd(&sZero, zc); atomicAdd(&sNz, nz);
  __syncthreads();
  if (tid==0) {
    flags[0] = (sBig > 64) || (sZero > 900);
    flags[1] = (sNz == 0);
  }
}

struct FPtrs { const void* p[20]; };
__global__ __launch_bounds__(256) void convf_kernel(
    const int* __restrict__ flags, FPtrs ptrs, float* __restrict__ wcf)
{
  const int start[21] = {0,49152,98304,147456,196608,196992,197376,197760,198144,
    198164,218644,239124,288276,337428,353812,353940,370324,370452,370455,370839,371223};
  int i = blockIdx.x*256 + threadIdx.x;
  if (i >= W_TOT) return;
  int arr = 0;
  #pragma unroll
  for (int a=1; a<20; ++a) arr += (i >= start[a]);
  int local = i - start[arr];
  wcf[i] = ldx(ptrs.p[arr], local, flags[0]);
}

__global__ __launch_bounds__(256) void idxconv_kernel(
    const int* __restrict__ flags,
    const int* __restrict__ nt, const int* __restrict__ ei, const int* __restrict__ et,
    int* __restrict__ nt32, int* __restrict__ ei32, int* __restrict__ et32)
{
  int i = blockIdx.x*256 + threadIdx.x;
  if (i >= 1000000) return;
  int w = flags[1] ? 2 : 1;
  if (i < 40000)        nt32[i] = nt[(long)i*w];
  else if (i < 680000)  { int j=i-40000;  ei32[j] = ei[(long)j*w]; }
  else                  { int j=i-680000; et32[j] = et[(long)j*w]; }
}

// zinit: fused init of perm/pcnt/nperm/pc2/mxkey/sumex/deg (grid 625*256 = N*H)
__global__ __launch_bounds__(256) void zinit_kernel(
    int* __restrict__ perm, int* __restrict__ pc,
    int* __restrict__ nperm, int* __restrict__ pc2,
    unsigned* __restrict__ mxkey, float* __restrict__ sumex, int* __restrict__ deg)
{
  int i = blockIdx.x*256 + threadIdx.x;
  if (i < 40448) perm[i] = -1;
  if (i < 12) pc[i] = 0;
  if (i < 40320) nperm[i] = -1;
  if (i < 16) pc2[i] = 0;
  mxkey[i] = fmono(-1e30f);
  sumex[i] = 0.f;
  if (i < N_) deg[i] = 0;
}

__global__ __launch_bounds__(256) void cnt_kernel(
    const int* __restrict__ keys, int n, int ntypes, int* __restrict__ gcnt)
{
  __shared__ int lh[8];
  if (threadIdx.x < ntypes) lh[threadIdx.x] = 0;
  __syncthreads();
  int i = blockIdx.x*256 + threadIdx.x;
  if (i < n) atomicAdd(&lh[keys[i]], 1);
  __syncthreads();
  if (threadIdx.x < ntypes && lh[threadIdx.x])
    atomicAdd(&gcnt[threadIdx.x], lh[threadIdx.x]);
}
// node groups 128-aligned (gemmt2 has 128-row blocks -> must be type-uniform)
__global__ void pofs_kernel(int* __restrict__ pc){
  if (threadIdx.x==0 && blockIdx.x==0) {
    pc[8] = 0;
    pc[9] = (pc[0]+127)&~127;
    pc[10] = pc[9] + ((pc[1]+127)&~127);
  }
}
// edge groups 64-aligned (gemmbd has 64-row blocks)
__global__ void eofs_kernel(int* __restrict__ pc2){
  if (threadIdx.x==0 && blockIdx.x==0) {
    pc2[10] = 0;
    #pragma unroll
    for (int r=1;r<R_;++r) pc2[10+r] = pc2[10+r-1] + ((pc2[r-1]+63)&~63);
  }
}
__global__ __launch_bounds__(256) void scat_kernel(
    const int* __restrict__ keys, int n, int ntypes,
    const int* __restrict__ ofs, int* __restrict__ fill, int* __restrict__ perm)
{
  __shared__ int lh[8];
  __shared__ int lbase[8];
  if (threadIdx.x < ntypes) lh[threadIdx.x] = 0;
  __syncthreads();
  int i = blockIdx.x*256 + threadIdx.x;
  int t = 0, rank = 0;
  bool ok = (i < n);
  if (ok) { t = keys[i]; rank = atomicAdd(&lh[t], 1); }
  __syncthreads();
  if (threadIdx.x < ntypes)
    lbase[threadIdx.x] = lh[threadIdx.x] ? atomicAdd(&fill[threadIdx.x], lh[threadIdx.x]) : 0;
  __syncthreads();
  if (ok) perm[ofs[t] + lbase[t] + rank] = i;
}

// prepA: raT[r][h][m][d] = rel_att[r][h][d][m]
__global__ __launch_bounds__(256) void prepA_kernel(
    const float* __restrict__ wcf, float* __restrict__ raT)
{
  int i = blockIdx.x*256 + threadIdx.x;
  if (i >= 20480) return;
  int d = i & 31, m = (i>>5) & 31, rh = i >> 10;
  raT[i] = wcf[W_RATT + (rh*32 + d)*32 + m];
}

// prepB: MT[k][i*128+col] = sum_j Wak_k[col,j]*Wkl[i,j];  ck[k][col] = sum_j Wak_k[col,j]*bkl[j]
__global__ __launch_bounds__(128) void prepB_kernel(
    const float* __restrict__ wcf, float* __restrict__ MT, float* __restrict__ ck)
{
  int col = threadIdx.x, i = blockIdx.x, k = blockIdx.y;
  const float* wak = wcf + W_WAK + k*16384 + col*128;
  const float* wkl = wcf + W_WKL + i*128;
  float acc = 0.f, accC = 0.f;
  #pragma unroll 8
  for (int j=0;j<128;++j) {
    float a = wak[j];
    acc  += a * wkl[j];
    if (i==0) accC += a * wcf[W_BKL + j];
  }
  MT[k*16384 + i*128 + col] = acc;
  if (i==0) ck[k*128 + col] = accC;
}

// prepT: transpose a [128k][128col] f32/bf16 matrix into split bf16 [col][k] hi|lo slots.
struct TPtrs { const void* p[16]; int soff[16]; int doff[16]; };
__global__ __launch_bounds__(256) void prepT_kernel(
    TPtrs tp, const int* __restrict__ flags, int xmode, u16* __restrict__ dst)
{
  __shared__ float T[128][33];
  int m = blockIdx.y;
  int c0 = blockIdx.x * 32;
  int tid = threadIdx.x;
  int xf = xmode ? 1 : flags[0];
  const void* src = tp.p[m];
  long sb = tp.soff[m];
  {
    int k = tid >> 1, ch = (tid & 1) * 16;
    #pragma unroll
    for (int j=0;j<16;++j)
      T[k][ch+j] = ldx(src, sb + (long)k*128 + c0 + ch + j, xf);
  }
  __syncthreads();
  int col = tid >> 3, k0 = (tid & 7) * 16;
  unsigned hp[8], lp[8];
  #pragma unroll
  for (int j=0;j<8;++j)
    split2(T[k0+2*j][col], T[k0+2*j+1][col], hp[j], lp[j]);
  u16* dh = dst + tp.doff[m] + (long)(c0+col)*128 + k0;
  ((uint4*)dh)[0] = uint4{hp[0],hp[1],hp[2],hp[3]};
  ((uint4*)dh)[1] = uint4{hp[4],hp[5],hp[6],hp[7]};
  u16* dl = dh + 16384;
  ((uint4*)dl)[0] = uint4{lp[0],lp[1],lp[2],lp[3]};
  ((uint4*)dl)[1] = uint4{lp[4],lp[5],lp[6],lp[7]};
}

// ---------------------------------------------------------------------------
// gemmt2 (MFMA hybrid, r14 structure): block = 128 rows x 128 cols, 4 waves.
// A: per-lane direct global loads in fragment layout, transform in-register.
// W: LDS-staged per kc (shared by 4 waves), register-prefetched across the barrier.
// obf[y]: write that y-slot's output as packed bf16 — ACTIVE ONLY when flags[0]==0
// (bf16 harness); f32 harness path is bit-identical to the f32 pipeline.
struct GC4 { const float* x[4]; int woff[4]; int boff[4]; int typed[4]; int obf[4]; };
__global__ __launch_bounds__(256) void gemmt2_kernel(
    GC4 cfg, const int* __restrict__ flags, int xmode,
    const u16* __restrict__ Wt, const float* __restrict__ wcf,
    const int* __restrict__ perm, const int* __restrict__ nt,
    int dotmode, const float* __restrict__ qlin, const float* __restrict__ ck,
    int powmode, const float* __restrict__ sattp, int wmode,
    float* __restrict__ out, long yostride)
{
  __shared__ u16 Wh[4096], Wl[4096];   // 16 KB
  __shared__ int ridx[128];
  __shared__ int tblk_s;
  int tid = threadIdx.x;
  int y = blockIdx.y;
  int row0 = blockIdx.x*128;
  if (tid < 128) {
    int rr = row0 + tid;
    int rg = perm ? perm[rr] : (rr < N_ ? rr : -1);
    ridx[tid] = rg;
    if (tid==0) tblk_s = (perm && nt && rg>=0) ? nt[rg] : 0;
  }
  __syncthreads();
  if (ridx[0] < 0) return;        // fully padded block (128-aligned groups -> uniform)
  int tblk = cfg.typed[y] ? tblk_s : 0;
  const u16* Wg = Wt + cfg.woff[y] + tblk*32768;
  const void* X = (const void*)cfg.x[y];
  int f0 = flags[0];
  int xf = xmode ? 1 : f0;
  int wlo_on = wmode ? 1 : f0;

  int lane = tid & 63;
  int wv   = tid >> 6;
  int lrow = lane & 15;
  int lk   = (lane >> 4) << 3;     // 0,8,16,24
  int rbase = wv*32;

  // this lane's two A rows (m=0,1); padded rows clamp to 0 (outputs guard-skipped)
  int sr0i = ridx[rbase + lrow];
  int sr1i = ridx[rbase + lrow + 16];
  long s0 = (sr0i < 0) ? 0 : (long)sr0i;
  long s1 = (sr1i < 0) ? 0 : (long)sr1i;

  // W staging partition (col-major table [col][32k] per kc chunk)
  int sr = tid >> 1;               // staging col 0..127
  int sh = (tid & 1) * 16;         // staging k offset 0/16
  int sp  = (sr >> 1) & 3;         // chunk-swizzle key
  int sc0 = (sh >> 3) ^ sp;
  int sc1 = ((sh >> 3) + 1) ^ sp;

  f32x4 acc[2][8];
  #pragma unroll
  for (int m=0;m<2;++m)
    #pragma unroll
    for (int n=0;n<8;++n) acc[m][n] = f32x4{0.f,0.f,0.f,0.f};

  // ---- prefetch registers ----
  float4 fa0, fa1, fb0, fb1;                 // f32 A rows (r0: fa*, r1: fb*)
  uint4  ua = {0,0,0,0}, ub = {0,0,0,0};     // bf16 A raw
  float  scp0 = 0.f, scp1 = 0.f;             // powmode per-row scales
  uint4  pw0, pw1, pw2 = {0,0,0,0}, pw3 = {0,0,0,0};   // W hi/lo

  // prologue: issue loads for kc=0
  if (xf) {
    const float4* x0 = reinterpret_cast<const float4*>((const float*)X + s0*128 + lk);
    const float4* x1 = reinterpret_cast<const float4*>((const float*)X + s1*128 + lk);
    fa0=x0[0]; fa1=x0[1]; fb0=x1[0]; fb1=x1[1];
    if (powmode) { scp0 = sattp[s0*4]; scp1 = sattp[s1*4]; }
  } else {
    ua = *reinterpret_cast<const uint4*>((const u16*)X + s0*128 + lk);
    ub = *reinterpret_cast<const uint4*>((const u16*)X + s1*128 + lk);
  }
  {
    const u16* gh = Wg + sr*128 + sh;
    pw0 = ((const uint4*)gh)[0]; pw1 = ((const uint4*)gh)[1];
    if (wlo_on) { pw2 = ((const uint4*)(gh+16384))[0]; pw3 = ((const uint4*)(gh+16384))[1]; }
  }

  for (int kc=0;kc<4;++kc) {
    // ---- transform current prefetched A into fragments (register-only) ----
    s16x8 ah0, ah1, al0, al1;
    if (xf) {
      float t0[8] = {fa0.x,fa0.y,fa0.z,fa0.w, fa1.x,fa1.y,fa1.z,fa1.w};
      float t1[8] = {fb0.x,fb0.y,fb0.z,fb0.w, fb1.x,fb1.y,fb1.z,fb1.w};
      if (powmode) {
        #pragma unroll
        for (int j=0;j<8;++j) {
          float v0 = t0[j], v1 = t1[j];
          if (y==0)      { t0[j] = v0*scp0;    t1[j] = v1*scp1; }
          else if (y==1) { t0[j] = v0*v0*scp0; t1[j] = v1*v1*scp1; }
          else {
            float a3 = v0*v0*v0*scp0, b3 = v1*v1*v1*scp1;
            t0[j] = (a3==0.f) ? 0.f : copysignf(cbrtf(fabsf(a3)+1e-18f), a3);
            t1[j] = (b3==0.f) ? 0.f : copysignf(cbrtf(fabsf(b3)+1e-18f), b3);
          }
        }
      }
      unsigned h0[4], l0[4], h1[4], l1[4];
      #pragma unroll
      for (int j=0;j<4;++j) {
        split2(t0[2*j], t0[2*j+1], h0[j], l0[j]);
        split2(t1[2*j], t1[2*j+1], h1[j], l1[j]);
      }
      uint4 H0{h0[0],h0[1],h0[2],h0[3]}, L0{l0[0],l0[1],l0[2],l0[3]};
      uint4 H1{h1[0],h1[1],h1[2],h1[3]}, L1{l1[0],l1[1],l1[2],l1[3]};
      ah0 = *reinterpret_cast<s16x8*>(&H0); al0 = *reinterpret_cast<s16x8*>(&L0);
      ah1 = *reinterpret_cast<s16x8*>(&H1); al1 = *reinterpret_cast<s16x8*>(&L1);
    } else {
      ah0 = *reinterpret_cast<s16x8*>(&ua);   // bf16 input: hi == raw bits, lo == 0
      ah1 = *reinterpret_cast<s16x8*>(&ub);
    }
    uint4 WH0 = pw0, WH1 = pw1, WL0 = pw2, WL1 = pw3;

    __syncthreads();               // all waves done reading W tile kc-1
    ((uint4*)Wh)[sr*4 + sc0] = WH0;
    ((uint4*)Wh)[sr*4 + sc1] = WH1;
    if (wlo_on) {
      ((uint4*)Wl)[sr*4 + sc0] = WL0;
      ((uint4*)Wl)[sr*4 + sc1] = WL1;
    }
    // ---- issue next-tile loads (latency hides under barrier + MFMA) ----
    if (kc < 3) {
      int kn_ = kc + 1;
      if (xf) {
        const float4* x0 = reinterpret_cast<const float4*>((const float*)X + s0*128 + kn_*32 + lk);
        const float4* x1 = reinterpret_cast<const float4*>((const float*)X + s1*128 + kn_*32 + lk);
        fa0=x0[0]; fa1=x0[1]; fb0=x1[0]; fb1=x1[1];
        if (powmode) { scp0 = sattp[s0*4 + kn_]; scp1 = sattp[s1*4 + kn_]; }
      } else {
        ua = *reinterpret_cast<const uint4*>((const u16*)X + s0*128 + kn_*32 + lk);
        ub = *reinterpret_cast<const uint4*>((const u16*)X + s1*128 + kn_*32 + lk);
      }
      const u16* gh = Wg + sr*128 + kn_*32 + sh;
      pw0 = ((const uint4*)gh)[0]; pw1 = ((const uint4*)gh)[1];
      if (wlo_on) { pw2 = ((const uint4*)(gh+16384))[0]; pw3 = ((const uint4*)(gh+16384))[1]; }
    }
    __syncthreads();               // W tile kc ready
    // ---- fragments + MFMA ----
    #pragma unroll
    for (int n=0;n<8;++n) {
      int col = n*16 + lrow;
      int ib = col*32 + (lk ^ (((col>>1)&3)<<3));
      s16x8 bh = *(const s16x8*)(Wh + ib);
      acc[0][n] = __builtin_amdgcn_mfma_f32_16x16x32_bf16(ah0, bh, acc[0][n], 0,0,0);
      acc[1][n] = __builtin_amdgcn_mfma_f32_16x16x32_bf16(ah1, bh, acc[1][n], 0,0,0);
      if (xf) {
        acc[0][n] = __builtin_amdgcn_mfma_f32_16x16x32_bf16(al0, bh, acc[0][n], 0,0,0);
        acc[1][n] = __builtin_amdgcn_mfma_f32_16x16x32_bf16(al1, bh, acc[1][n], 0,0,0);
      }
      if (wlo_on) {
        s16x8 bl = *(const s16x8*)(Wl + ib);
        acc[0][n] = __builtin_amdgcn_mfma_f32_16x16x32_bf16(ah0, bl, acc[0][n], 0,0,0);
        acc[1][n] = __builtin_amdgcn_mfma_f32_16x16x32_bf16(ah1, bl, acc[1][n], 0,0,0);
      }
    }
  }

  // D layout per 16x16 frag: row = (lane>>4)*4 + r, col = lane&15.
  int rq = (lane >> 4) << 2;
  if (!dotmode) {
    float b[8];
    if (cfg.boff[y] >= 0) {
      const float* bp = wcf + cfg.boff[y] + tblk*128;
      #pragma unroll
      for (int n=0;n<8;++n) b[n] = bp[n*16 + lrow];
    } else {
      #pragma unroll
      for (int n=0;n<8;++n) b[n] = 0.f;
    }
    int ob = cfg.obf[y] && !f0;
    #pragma unroll
    for (int m=0;m<2;++m) {
      #pragma unroll
      for (int r=0;r<4;++r) {
        int rowl = rbase + m*16 + rq + r;
        int rowg = ridx[rowl];
        if (rowg < 0) continue;
        if (ob) {
          u16* op = (u16*)(out + (long)y*yostride) + (long)rowg*128 + lrow;
          #pragma unroll
          for (int n=0;n<8;++n) op[n*16] = f2bf(acc[m][n][r] + b[n]);
        } else {
          float* op = out + (long)y*yostride + (long)rowg*128 + lrow;
          #pragma unroll
          for (int n=0;n<8;++n) op[n*16] = acc[m][n][r] + b[n];
        }
      }
    }
  } else {
    float ckv[8];
    #pragma unroll
    for (int n=0;n<8;++n) ckv[n] = ck[y*128 + n*16 + lrow];
    #pragma unroll
    for (int m=0;m<2;++m) {
      #pragma unroll
      for (int r=0;r<4;++r) {
        int rowl = rbase + m*16 + rq + r;
        int rowg = ridx[rowl];
        float d = 0.f;
        if (rowg >= 0) {
          const float* qp = qlin + (long)rowg*128 + lrow;
          #pragma unroll
          for (int n=0;n<8;++n) d += (acc[m][n][r] + ckv[n]) * qp[n*16];
        }
        #pragma unroll
        for (int msk=1; msk<16; msk<<=1) d += __shfl_xor(d, msk, 64);
        if (lrow==0 && rowg>=0) out[(long)rowg*4 + y] = 1.f/(1.f+expf(-d));
      }
    }
  }
}

// ---------------------------------------------------------------------------
// gemmbd: block-diagonal (4 heads x 32x32) GEMM, 64 rows x 128 cols per block.
__global__ __launch_bounds__(256) void gemmbd_kernel(
    const float* __restrict__ X,
    const float* __restrict__ Wtab, int wsel,
    const int* __restrict__ perm, const int* __restrict__ gsrc, const int* __restrict__ et,
    float* __restrict__ out)
{
  __shared__ float As[64*152];    // [row][h*36 + m], bank-staggered
  __shared__ float Ws[4096];
  __shared__ int ridx[64];
  __shared__ int rsel_s;
  int tid = threadIdx.x;
  int row0 = blockIdx.x*64;
  if (tid < 64) {
    int rr = row0 + tid;
    int pe = perm ? perm[rr] : (rr < N_ ? rr : -1);
    ridx[tid] = pe;
    if (tid == 0) rsel_s = (wsel && pe >= 0) ? et[pe] : 0;
  }
  __syncthreads();
  if (ridx[0] < 0) return;
  const float* Wg = Wtab + (long)(wsel ? rsel_s : 0)*4096;
  #pragma unroll
  for (int j=0;j<4;++j)
    *reinterpret_cast<float4*>(&Ws[j*1024 + tid*4]) =
      *reinterpret_cast<const float4*>(Wg + j*1024 + tid*4);
  {
    int sar = tid >> 2, sh = tid & 3;
    int pe_s = ridx[sar];
    int arow = (pe_s < 0) ? -1 : (gsrc ? gsrc[pe_s] : pe_s);
    float* dst = &As[sar*152 + sh*36];
    if (arow < 0) {
      #pragma unroll
      for (int j=0;j<8;++j) *reinterpret_cast<float4*>(dst + j*4) = float4{0.f,0.f,0.f,0.f};
    } else {
      const float4* s4 = reinterpret_cast<const float4*>(X + (long)arow*128 + sh*32);
      #pragma unroll
      for (int j=0;j<8;++j) *reinterpret_cast<float4*>(dst + j*4) = s4[j];
    }
  }
  __syncthreads();
  int rg_ = tid >> 5, cg = tid & 31;
  int h = cg >> 3, c4 = (cg & 7)*4;
  float acc[8][4];
  #pragma unroll
  for (int r=0;r<8;++r){ acc[r][0]=0.f; acc[r][1]=0.f; acc[r][2]=0.f; acc[r][3]=0.f; }
  #pragma unroll
  for (int mq=0;mq<8;++mq) {
    float wv[4][4];
    #pragma unroll
    for (int i=0;i<4;++i) {
      float4 wt = *reinterpret_cast<const float4*>(&Ws[h*1024 + (mq*4+i)*32 + c4]);
      wv[i][0]=wt.x; wv[i][1]=wt.y; wv[i][2]=wt.z; wv[i][3]=wt.w;
    }
    #pragma unroll
    for (int r=0;r<8;++r) {
      float4 a4 = *reinterpret_cast<const float4*>(&As[(rg_*8+r)*152 + h*36 + mq*4]);
      float av[4] = {a4.x,a4.y,a4.z,a4.w};
      #pragma unroll
      for (int i=0;i<4;++i) {
        acc[r][0]+=av[i]*wv[i][0]; acc[r][1]+=av[i]*wv[i][1];
        acc[r][2]+=av[i]*wv[i][2]; acc[r][3]+=av[i]*wv[i][3];
      }
    }
  }
  #pragma unroll
  for (int r=0;r<8;++r) {
    int pe = ridx[rg_*8+r];
    if (pe < 0) continue;
    float4 o = {acc[r][0],acc[r][1],acc[r][2],acc[r][3]};
    *reinterpret_cast<float4*>(out + (long)pe*128 + h*32 + c4) = o;
  }
}

// ---------------------------------------------------------------------------
__global__ __launch_bounds__(256) void epass_kernel(
    const float* __restrict__ kn, const float* __restrict__ qtr, const float* __restrict__ wcf,
    const int* __restrict__ ei, const int* __restrict__ et, int rsel,
    float* __restrict__ logits, unsigned* __restrict__ mxkey, int* __restrict__ deg)
{
  int gid = blockIdx.x*256 + threadIdx.x;   // E*H
  int e = gid >> 2, h = gid & 3;
  if (et[e] != rsel) return;
  int s = ei[e], t = ei[E_+e];
  const float4* ka = reinterpret_cast<const float4*>(kn + (long)s*128 + h*32);
  const float4* qa = reinterpret_cast<const float4*>(qtr + (long)t*128 + h*32);
  float acc = 0.f;
  #pragma unroll
  for (int i=0;i<8;++i) {
    float4 a = ka[i], b = qa[i];
    acc += a.x*b.x + a.y*b.y + a.z*b.z + a.w*b.w;
  }
  float lg = acc * wcf[W_PRI + rsel*H_+h] * 0.17677669529663687f;
  logits[gid] = lg;
  atomicMax(mxkey + t*H_+h, fmono(lg));
  if (h==0) atomicAdd(deg + t, 1);
}

__global__ __launch_bounds__(256) void eexp_kernel(
    const int* __restrict__ ei, float* __restrict__ logits,
    const unsigned* __restrict__ mxkey, float* __restrict__ sumex)
{
  int gid = blockIdx.x*256 + threadIdx.x;
  int e = gid >> 2, h = gid & 3;
  int t = ei[E_+e];
  float d = fminf(logits[gid] - monof(mxkey[t*H_+h]), 0.f);
  float ex = expf(d);
  if (e < N_) logits[gid] = ex;    // only first-N edges' ex are ever read (satt)
  atomicAdd(sumex + t*H_+h, ex);
}

// satt[n*4+h] = deg[n] * ex[n*4+h] / (sumex[tgt[n]*4+h] + 1e-16)
__global__ __launch_bounds__(256) void satt_kernel(
    const int* __restrict__ ei, const float* __restrict__ ex, const float* __restrict__ sumex,
    const int* __restrict__ deg, float* __restrict__ satt)
{
  int i = blockIdx.x*256 + threadIdx.x;   // N*H
  int n = i >> 2, h = i & 3;
  int t = ei[E_+n];
  satt[i] = (float)deg[n] * ex[i] / (sumex[t*H_+h] + 1e-16f);
}

// gatemix: res = sum_k t_k·ag_k; h = gelu_exact(res). 2 elems/thread.
// bf16 harness (!flags[0]): ag read as bf16, hbuf written bf16; else all f32.
__global__ __launch_bounds__(256) void gatemix_kernel(
    const int* __restrict__ flags, const float* __restrict__ tval,
    const float* __restrict__ ag0, const float* __restrict__ ag1, const float* __restrict__ ag2,
    float* __restrict__ hout)
{
  long gid = ((long)blockIdx.x*256 + threadIdx.x) * 2;   // N*128 elems, 2 per thread
  int n = (int)(gid >> 7);
  float t0 = tval[n*4+0], t1 = tval[n*4+1], t2 = tval[n*4+2];
  float r0, r1;
  if (!flags[0]) {
    unsigned a0 = *reinterpret_cast<const unsigned*>((const u16*)ag0 + gid);
    unsigned a1 = *reinterpret_cast<const unsigned*>((const u16*)ag1 + gid);
    unsigned a2 = *reinterpret_cast<const unsigned*>((const u16*)ag2 + gid);
    r0 = t0*__uint_as_float(a0<<16) + t1*__uint_as_float(a1<<16) + t2*__uint_as_float(a2<<16);
    r1 = t0*__uint_as_float(a0&0xFFFF0000u) + t1*__uint_as_float(a1&0xFFFF0000u)
       + t2*__uint_as_float(a2&0xFFFF0000u);
  } else {
    float2 a0 = *reinterpret_cast<const float2*>(ag0 + gid);
    float2 a1 = *reinterpret_cast<const float2*>(ag1 + gid);
    float2 a2 = *reinterpret_cast<const float2*>(ag2 + gid);
    r0 = t0*a0.x + t1*a1.x + t2*a2.x;
    r1 = t0*a0.y + t1*a1.y + t2*a2.y;
  }
  float g0 = 0.5f*r0*(1.f+erff(r0*0.70710678118654752f));
  float g1 = 0.5f*r1*(1.f+erff(r1*0.70710678118654752f));
  if (!flags[0]) {
    unsigned o = (unsigned)f2bf(g0) | ((unsigned)f2bf(g1)<<16);
    *reinterpret_cast<unsigned*>((u16*)hout + gid) = o;
  } else {
    *reinterpret_cast<float2*>(hout + gid) = float2{g0, g1};
  }
}

__global__ __launch_bounds__(256) void lnf_kernel(
    const float* __restrict__ trans, const void* __restrict__ x, const int* __restrict__ flags,
    const int* __restrict__ nt, const float* __restrict__ wcf, void* __restrict__ outv)
{
  int wave = threadIdx.x >> 6, lane = threadIdx.x & 63;
  int n = blockIdx.x*4 + wave;
  int j = lane*2;
  int xf = flags[0];
  int t = nt[n];
  float alpha = 1.f/(1.f+expf(-wcf[W_SKIP+t]));
  long base = (long)n*128 + j;
  float y0 = alpha*trans[base]   + (1.f-alpha)*ldx(x, base,   xf);
  float y1 = alpha*trans[base+1] + (1.f-alpha)*ldx(x, base+1, xf);
  float mu = wredsum(y0+y1) * (1.f/128.f);
  float d0 = y0-mu, d1 = y1-mu;
  float var = wredsum(d0*d0+d1*d1) * (1.f/128.f);
  float inv = rsqrtf(var + 1e-5f);
  float o0 = d0*inv*wcf[W_LNG + t*128+j]   + wcf[W_LNB + t*128+j];
  float o1 = d1*inv*wcf[W_LNG + t*128+j+1] + wcf[W_LNB + t*128+j+1];
  if (xf) {
    ((float*)outv)[base]   = o0;
    ((float*)outv)[base+1] = o1;
  } else {
    unsigned o = (unsigned)f2bf(o0) | ((unsigned)f2bf(o1)<<16);
    *reinterpret_cast<unsigned*>(((u16*)outv)+base) = o;
  }
}

// ---------------------------------------------------------------------------
extern "C" void kernel_launch(void* const* d_in, const int* in_sizes, int n_in,
                              void* d_out, int out_size, void* d_ws, size_t ws_size,
                              hipStream_t stream) {
  char* w = (char*)d_ws;
  int*      flags = (int*)     (w + OFF_FLAGS);
  float*    wcf   = (float*)   (w + OFF_WCF);
  u16*      wtb   = (u16*)     (w + OFF_WCF);   // split-transposed weight tables overlay
  int*      nt32  = (int*)     (w + OFF_NT32);
  int*      ei32  = (int*)     (w + OFF_EI32);
  int*      et32  = (int*)     (w + OFF_ET32);
  int*      perm  = (int*)     (w + OFF_PERM);
  int*      pcnt  = (int*)     (w + OFF_PCNT);
  int*      pc2   = (int*)     (w + OFF_PCNT + 128);
  float*    raT   = (float*)   (w + OFF_TVAL);   // raT -> satt/tval (disjoint lifetimes)
  float*    satt  = (float*)   (w + OFF_TVAL);
  float*    tval  = (float*)   (w + OFF_TVAL);
  int*      nperm = (int*)     (w + OFF_NPERM);
  float*    logits= (float*)   (w + OFF_LOG);
  unsigned* mxkey = (unsigned*)(w + OFF_LOG + 5120000);
  float*    sumex = (float*)   (w + OFF_LOG + 5760000);
  int*      deg   = (int*)     (w + OFF_LOG + 6400000);
  float*    MT    = (float*)   (w + OFF_LOG);            // overlays dead softmax scratch
  float*    ckb   = (float*)   (w + OFF_LOG + 786432);
  u16*      mtt   = (u16*)     (w + OFF_LOG + 1048576);  // split-transposed MT (3 slots)
  float*    qn    = (float*)   (w + OFF_QN);
  float*    ag0   = (float*)   (w + OFF_QN);    // bf16-packed on bf16 harness
  float*    trans = (float*)   (w + OFF_QN);
  float*    kn    = (float*)   (w + OFF_KN);
  float*    ag1   = (float*)   (w + OFF_KN);
  float*    vn    = (float*)   (w + OFF_VN);
  float*    ag2   = (float*)   (w + OFF_VN);
  float*    qlin  = (float*)   (w + OFF_QLIN);
  float*    hbuf  = (float*)   (w + OFF_QLIN);  // bf16-packed on bf16 harness
  float*    qtrb  = (float*)   (w + OFF_QTR);
  float*    vp    = (float*)   (w + OFF_QTR);

  // s0: dtype detect + canonicalize
  detect_kernel<<<1,256,0,stream>>>((const u16*)d_in[0], (const int*)d_in[1], flags);
  FPtrs fp;
  fp.p[0]=d_in[5];  fp.p[1]=d_in[7];  fp.p[2]=d_in[9];  fp.p[3]=d_in[11];
  fp.p[4]=d_in[6];  fp.p[5]=d_in[8];  fp.p[6]=d_in[10]; fp.p[7]=d_in[12];
  fp.p[8]=d_in[13]; fp.p[9]=d_in[14]; fp.p[10]=d_in[15];fp.p[11]=d_in[16];
  fp.p[12]=d_in[17];fp.p[13]=d_in[18];fp.p[14]=d_in[19];fp.p[15]=d_in[20];
  fp.p[16]=d_in[21];fp.p[17]=d_in[22];fp.p[18]=d_in[23];fp.p[19]=d_in[24];
  convf_kernel<<<1451,256,0,stream>>>(flags, fp, wcf);
  idxconv_kernel<<<3907,256,0,stream>>>(flags, (const int*)d_in[1],
                                        (const int*)d_in[2], (const int*)d_in[3],
                                        nt32, ei32, et32);
  // s0.6: fused zero/init (perm, pcnt, nperm, pc2, softmax accumulators)
  zinit_kernel<<<625,256,0,stream>>>(perm, pcnt, nperm, pc2, mxkey, sumex, deg);
  // s0.7: node-type perm (128-aligned groups)
  cnt_kernel  <<<157,256,0,stream>>>(nt32, N_, T_, pcnt);
  pofs_kernel <<<1,64,0,stream>>>(pcnt);
  scat_kernel <<<157,256,0,stream>>>(nt32, N_, T_, pcnt+8, pcnt+4, perm);
  // s0.8: edge-type perm over first N edges (64-aligned groups)
  cnt_kernel  <<<157,256,0,stream>>>(et32, N_, R_, pc2);
  eofs_kernel <<<1,64,0,stream>>>(pc2);
  scat_kernel <<<157,256,0,stream>>>(et32, N_, R_, pc2+10, pc2+5, nperm);
  // s1: raT (reads W_RATT f32 — must precede prepT which overlays that region)
  prepA_kernel<<<80,256,0,stream>>>(wcf, raT);

  // s1.5: split-transposed bf16 weight tables from original inputs (overlay dead wcf slots)
  TPtrs tps;
  for (int t=0;t<3;++t) {
    tps.p[t]    = d_in[5];  tps.soff[t]    = t*16384; tps.doff[t]    = WT_Q   + t*32768;
    tps.p[3+t]  = d_in[7];  tps.soff[3+t]  = t*16384; tps.doff[3+t]  = WT_K   + t*32768;
    tps.p[6+t]  = d_in[9];  tps.soff[6+t]  = t*16384; tps.doff[6+t]  = WT_V   + t*32768;
    tps.p[9+t]  = d_in[11]; tps.soff[9+t]  = t*16384; tps.doff[9+t]  = WT_A   + t*32768;
    tps.p[13+t] = d_in[16]; tps.soff[13+t] = t*16384; tps.doff[13+t] = WT_WMK + t*32768;
  }
  tps.p[12] = d_in[18]; tps.soff[12] = 0; tps.doff[12] = WT_WQ;
  prepT_kernel<<<dim3(4,16),256,0,stream>>>(tps, flags, 0, wtb);

  // s2: q/k/v/qlin projections in ONE y=4 dispatch (all f32 outputs)
  GC4 cq;
  cq.x[0]=(const float*)d_in[0]; cq.x[1]=cq.x[0]; cq.x[2]=cq.x[0]; cq.x[3]=cq.x[0];
  cq.woff[0]=WT_Q; cq.woff[1]=WT_K; cq.woff[2]=WT_V; cq.woff[3]=WT_WQ;
  cq.boff[0]=W_QB; cq.boff[1]=W_KB; cq.boff[2]=W_VB; cq.boff[3]=W_BQ;
  cq.typed[0]=1; cq.typed[1]=1; cq.typed[2]=1; cq.typed[3]=0;
  cq.obf[0]=0; cq.obf[1]=0; cq.obf[2]=0; cq.obf[3]=0;
  gemmt2_kernel<<<dim3(316,4),256,0,stream>>>(cq, flags, 0, wtb, wcf, perm, nt32,
      0, nullptr, nullptr, 0, nullptr, 0, qn, 5120000);

  // s6: per-relation qtr (gemmbd) + edge pass (f32)
  for (int r=0; r<R_; ++r) {
    gemmbd_kernel<<<625,256,0,stream>>>(qn, raT + r*4096, 0, nullptr, nullptr, nullptr, qtrb);
    epass_kernel<<<5000,256,0,stream>>>(kn, qtrb, wcf, ei32, et32, r, logits, mxkey, deg);
  }
  // s7: exp + segment-sum
  eexp_kernel<<<5000,256,0,stream>>>(ei32, logits, mxkey, sumex);

  // s7.5: vp[n] = vn[src[n]] @ BD(rel_msg[et[n]])  (edge-type-sorted blocks)
  gemmbd_kernel<<<630,256,0,stream>>>(vn, wcf+W_RMSG, 1, nperm, ei32, et32, vp);

  // s7.75: satt = deg·ex/sumex  (softmax scratch dead after this)
  satt_kernel<<<625,256,0,stream>>>(ei32, logits, sumex, deg, satt);

  // s8.25: MT/ck into dead softmax region, then split-transpose MT -> mtt
  prepB_kernel<<<dim3(128,3),128,0,stream>>>(wcf, MT, ckb);
  TPtrs tpm;
  for (int i=0;i<16;++i){ tpm.p[i]=MT; tpm.soff[i]=0; tpm.doff[i]=0; }
  for (int k=0;k<3;++k){ tpm.soff[k]=k*16384; tpm.doff[k]=k*32768; }
  prepT_kernel<<<dim3(4,3),256,0,stream>>>(tpm, flags, 1, mtt);

  // s8.5: ag_k = pow_k(vp)·satt @ WMk[k]  (powmode; ag written bf16 on bf16 harness)
  GC4 cp;
  cp.x[0]=vp; cp.x[1]=vp; cp.x[2]=vp; cp.x[3]=vp;
  cp.woff[0]=WT_WMK; cp.woff[1]=WT_WMK+32768; cp.woff[2]=WT_WMK+65536; cp.woff[3]=0;
  cp.boff[0]=-1; cp.boff[1]=-1; cp.boff[2]=-1; cp.boff[3]=-1;
  cp.typed[0]=0; cp.typed[1]=0; cp.typed[2]=0; cp.typed[3]=0;
  cp.obf[0]=1; cp.obf[1]=1; cp.obf[2]=1; cp.obf[3]=0;
  gemmt2_kernel<<<dim3(313,3),256,0,stream>>>(cp, flags, 1, wtb, wcf, nullptr, nullptr,
      0, nullptr, nullptr, 1, satt, 0, ag0, 5120000);

  // s9: gate scalars (dot-mode; A=ag follows harness dtype via xmode=0; MT lo kept)
  GC4 cd;
  cd.x[0]=ag0; cd.x[1]=ag1; cd.x[2]=ag2; cd.x[3]=ag2;
  cd.woff[0]=0; cd.woff[1]=32768; cd.woff[2]=65536; cd.woff[3]=0;
  cd.boff[0]=-1; cd.boff[1]=-1; cd.boff[2]=-1; cd.boff[3]=-1;
  cd.typed[0]=0; cd.typed[1]=0; cd.typed[2]=0; cd.typed[3]=0;
  cd.obf[0]=0; cd.obf[1]=0; cd.obf[2]=0; cd.obf[3]=0;
  gemmt2_kernel<<<dim3(313,3),256,0,stream>>>(cd, flags, 0, mtt, wcf, nullptr, nullptr,
      1, qlin, ckb, 0, nullptr, 1, tval, 0);

  // s10: mix + gelu -> hbuf (bf16 on bf16 harness; overlays qlin, dead after dot-mode)
  gatemix_kernel<<<10000,256,0,stream>>>(flags, tval, ag0, ag1, ag2, hbuf);

  // s11: trans = typed(h, a_w, a_b)  (A=hbuf follows harness dtype via xmode=0)
  GC4 ct;
  ct.x[0]=hbuf; ct.x[1]=hbuf; ct.x[2]=hbuf; ct.x[3]=hbuf;
  ct.woff[0]=WT_A; ct.woff[1]=0; ct.woff[2]=0; ct.woff[3]=0;
  ct.boff[0]=W_AB; ct.boff[1]=-1; ct.boff[2]=-1; ct.boff[3]=-1;
  ct.typed[0]=1; ct.typed[1]=0; ct.typed[2]=0; ct.typed[3]=0;
  ct.obf[0]=0; ct.obf[1]=0; ct.obf[2]=0; ct.obf[3]=0;
  gemmt2_kernel<<<dim3(316,1),256,0,stream>>>(ct, flags, 0, wtb, wcf, perm, nt32,
      0, nullptr, nullptr, 0, nullptr, 0, trans, 0);

  // s12: skip-mix + per-type LayerNorm -> out
  lnf_kernel<<<10000,256,0,stream>>>(trans, d_in[0], flags, nt32, wcf, d_out);

  (void)in_sizes; (void)n_in; (void)out_size; (void)ws_size;
}